// Round 11
// baseline (332.071 us; speedup 1.0000x reference)
//
#include <hip/hip_runtime.h>
#include <math.h>

#define SEQ     1024
#define NBATCH  8
#define NTOK    8192        // NBATCH*SEQLEN
#define DMODEL  512
#define DINNER  1024
#define NHEADS  16
#define DPROJ   2192
#define DPROJP  2304        // padded to multiple of 128
#define CONVDIM 1152
#define DFFN    2048

typedef short bf16x8 __attribute__((ext_vector_type(8)));
typedef float f32x4  __attribute__((ext_vector_type(4)));

__device__ inline unsigned short f2bf(float f) {
  union { float f; unsigned int u; } v; v.f = f;
  unsigned int u = v.u;
  return (unsigned short)((u + 0x7FFFu + ((u >> 16) & 1u)) >> 16);
}
__device__ inline float bf2f(unsigned short s) {
  union { unsigned int u; float f; } v; v.u = ((unsigned int)s) << 16;
  return v.f;
}

// fast transcendentals: native v_exp_f32 / v_rcp_f32 (~1e-7 rel err, far below
// the bf16 rounding these values feed into; ocml expf/erff are 25-60 instr).
__device__ inline float fexp(float x) { return __expf(x); }
__device__ inline float frcp(float x) { return __builtin_amdgcn_rcpf(x); }
__device__ inline float silu_f(float v) { return v * frcp(1.f + fexp(-v)); }
// erf via Abramowitz-Stegun 7.1.26, |err| <= 1.5e-7
__device__ inline float gelu_f(float v) {
  float x = v * 0.7071067811865476f;
  float ax = fabsf(x);
  float t = frcp(1.f + 0.3275911f * ax);
  float p = ((((1.061405429f * t - 1.453152027f) * t + 1.421413741f) * t
              - 0.284496736f) * t + 0.254829592f) * t;
  float er = copysignf(1.f - p * fexp(-ax * ax), x);
  return 0.5f * v * (1.f + er);
}

// XCD-aware swizzle (T1): consecutive HW-dispatched blocks round-robin the 8
// XCDs; remap so each XCD owns a CONTIGUOUS tile range (operand-panel L2 reuse).
// Bijective transpose of the 8 x (nwg/8) id matrix; requires nwg % 8 == 0
// (true for every launch here). R10 verified: ssd FETCH 40.9 -> 19.9 MB.
__device__ inline int xcd_swz(int flat, int nwg) {
  return (flat & 7) * (nwg >> 3) + (flat >> 3);
}

// async global->LDS, 16B per lane; lds base must be wave-uniform (lane*16 added by HW)
#define GLDS16(g, l)                                                         \
  __builtin_amdgcn_global_load_lds(                                          \
      (const __attribute__((address_space(1))) unsigned int*)(g),            \
      (__attribute__((address_space(3))) unsigned int*)(l), 16, 0, 0)

// ---------------- ALL bf16 conversions in ONE launch ----------------
__global__ __launch_bounds__(256)
void cvt_all(const float* __restrict__ u, const float* __restrict__ inw,
             const float* __restrict__ outw, const float* __restrict__ w1,
             const float* __restrict__ w2,
             unsigned short* __restrict__ u_bf, unsigned short* __restrict__ winb,
             unsigned short* __restrict__ woutb, unsigned short* __restrict__ w1b,
             unsigned short* __restrict__ w2b) {
  int i = blockIdx.x * 256 + threadIdx.x;
  const int nu = NTOK * DMODEL;
  const int n0 = DPROJP * DMODEL;
  const int n1 = DMODEL * DINNER;
  const int n2 = DFFN * DMODEL;
  const int n3 = DMODEL * DFFN;
  if (i < nu) {
    u_bf[i] = f2bf(u[i]);
  } else if ((i -= nu) < n0) {
    int r = i / DMODEL;
    winb[i] = (r < DPROJ) ? f2bf(inw[i]) : (unsigned short)0;
  } else if ((i -= n0) < n1) {
    woutb[i] = f2bf(outw[i]);
  } else if ((i -= n1) < n2) {
    w1b[i] = f2bf(w1[i]);
  } else if ((i -= n2) < n3) {
    w2b[i] = f2bf(w2[i]);
  }
}

// ---------------- bf16 MFMA GEMM: C[M,N] = A[M,K] @ B[N,K]^T ----------------
// 128x128 tile, 2x2 waves of 64x64, single-barrier double-buffered GLDS pipeline.
// (R1-proven structure; R2/R3/R4 restructurings all timed-equal or worse.)
// XCD swizzle: blocks sharing an A-panel (same by) land on the same XCD's L2.
// MODE 0: fp32 (+bias). MODE 1: bias+gelu->bf16. MODE 2: bf16, cols>=2176 also
// fp32 -> aux. MODE 3: bf16 PARTIAL at (ushort*)Cout + z*zstrideC (consumer sums).
template <int MODE>
__global__ __launch_bounds__(256)
void gemm_bt(const unsigned short* __restrict__ A, const unsigned short* __restrict__ B,
             void* __restrict__ Cout, const float* __restrict__ bias,
             float* __restrict__ aux, int Ksub, int lda, int Nreal, size_t zstrideC) {
  __shared__ unsigned short sA[2][128 * 32];
  __shared__ unsigned short sB[2][128 * 32];
  const int tid = threadIdx.x;
  // XCD-aware flat-id remap (all grids here have nwg % 8 == 0)
  const int nwg = gridDim.x * gridDim.y * gridDim.z;
  const int flat = blockIdx.x + gridDim.x * (blockIdx.y + gridDim.y * blockIdx.z);
  const int swz = xcd_swz(flat, nwg);
  const int bx = swz % gridDim.x;
  const int tmp = swz / gridDim.x;
  const int by = tmp % gridDim.y;
  const int bz = tmp / gridDim.y;
  const int lane = tid & 63;
  const int wave = tid >> 6;
  const int wm = wave >> 1, wn = wave & 1;
  const int arow = tid >> 2;               // 0..63
  const int acol = (tid & 3) << 3;

  const unsigned short* pA = A + (size_t)(by * 128 + arow) * lda + bz * Ksub + acol;
  const unsigned short* pB = B + (size_t)(bx * 128 + arow) * lda + bz * Ksub + acol;
  const size_t stride64 = (size_t)64 * lda;
  char* sAw[2] = { (char*)&sA[0][0] + wave * 1024, (char*)&sA[1][0] + wave * 1024 };
  char* sBw[2] = { (char*)&sB[0][0] + wave * 1024, (char*)&sB[1][0] + wave * 1024 };

  f32x4 acc[4][4];
#pragma unroll
  for (int i = 0; i < 4; i++)
#pragma unroll
    for (int j = 0; j < 4; j++) { f32x4 z = {0.f, 0.f, 0.f, 0.f}; acc[i][j] = z; }

  // prologue: stage k0=0 into buf 0
  GLDS16(pA, sAw[0]);
  GLDS16(pA + stride64, sAw[0] + 4096);
  GLDS16(pB, sBw[0]);
  GLDS16(pB + stride64, sBw[0] + 4096);
  pA += 32; pB += 32;
  __syncthreads();

  const int lrow = lane & 15;
  const int lkq = (lane >> 4) << 3;
  int cur = 0;
  for (int k0 = 0; k0 < Ksub; k0 += 32) {
    if (k0 + 32 < Ksub) {
      const int nxt = cur ^ 1;
      GLDS16(pA, sAw[nxt]);
      GLDS16(pA + stride64, sAw[nxt] + 4096);
      GLDS16(pB, sBw[nxt]);
      GLDS16(pB + stride64, sBw[nxt] + 4096);
      pA += 32; pB += 32;
    }
    bf16x8 af[4], bfr[4];
#pragma unroll
    for (int mi = 0; mi < 4; mi++)
      af[mi] = *(const bf16x8*)&sA[cur][(wm * 64 + mi * 16 + lrow) * 32 + lkq];
#pragma unroll
    for (int ni = 0; ni < 4; ni++)
      bfr[ni] = *(const bf16x8*)&sB[cur][(wn * 64 + ni * 16 + lrow) * 32 + lkq];
#pragma unroll
    for (int mi = 0; mi < 4; mi++)
#pragma unroll
      for (int ni = 0; ni < 4; ni++)
        acc[mi][ni] = __builtin_amdgcn_mfma_f32_16x16x32_bf16(af[mi], bfr[ni], acc[mi][ni], 0, 0, 0);
    __syncthreads();
    cur ^= 1;
  }

  const int row0 = by * 128 + wm * 64;
  const int col0 = bx * 128 + wn * 64;
  float* outf = (float*)Cout;
  unsigned short* outp16 = (unsigned short*)Cout + (size_t)bz * zstrideC;
#pragma unroll
  for (int mi = 0; mi < 4; mi++) {
#pragma unroll
    for (int ni = 0; ni < 4; ni++) {
      const int col = col0 + ni * 16 + lrow;
      if (col < Nreal) {
        const float bval = (MODE == 0 || MODE == 1) && bias ? bias[col] : 0.f;
#pragma unroll
        for (int r = 0; r < 4; r++) {
          const int row = row0 + mi * 16 + ((lane >> 4) << 2) + r;
          float v = acc[mi][ni][r] + bval;
          if (MODE == 1) {
            ((unsigned short*)Cout)[(size_t)row * Nreal + col] = f2bf(gelu_f(v));
          } else if (MODE == 2) {
            ((unsigned short*)Cout)[(size_t)row * Nreal + col] = f2bf(v);
            if (col >= 2176) aux[(size_t)row * 16 + (col - 2176)] = v;
          } else if (MODE == 3) {
            outp16[(size_t)row * Nreal + col] = f2bf(v);
          } else {
            outf[(size_t)row * Nreal + col] = v;
          }
        }
      }
    }
  }
}

// ---------------- merged: dt softplus (blocks 0..1023) + B/C conv (blocks 1024..1151) ----
__global__ __launch_bounds__(256)
void dt_conv_bc(const float* __restrict__ zdt, const float* __restrict__ dt_bias,
                float* __restrict__ dtf, float* __restrict__ dtb,
                const unsigned short* __restrict__ zxb, const float* __restrict__ cw,
                const float* __restrict__ cb,
                unsigned short* __restrict__ xbcf, unsigned short* __restrict__ xbcb) {
  const int tid = threadIdx.x;
  if (blockIdx.x < 1024) {
    // dt = softplus(zdt + dt_bias); layout [dir][(b*16+h)][t]
    int i = blockIdx.x * 256 + tid;             // 0 .. 262143
    int dir = i >> 17;
    int rem = i & 131071;
    int row = rem >> 10;                        // b*16+h
    int t = rem & 1023;
    int b = row >> 4, h = row & 15;
    int srow = (b << 10) + (dir ? (1023 - t) : t);
    float v = zdt[(size_t)srow * 16 + h] + dt_bias[h];
    float dt = (v > 20.f) ? v : log1pf(fexp(v));
    (dir ? dtb : dtf)[(row << 10) + t] = dt;
    return;
  }
  // conv+silu for B/C channels (128 ch), both dirs; xbc[row][128]
  const int bid = blockIdx.x - 1024;            // 0..127
  const int sx = bid & 15, b = bid >> 4;
  const int c128 = tid & 127;
  const int c = 1024 + c128;
  const int seg = sx * 2 + (tid >> 7);          // 0..31
  const int t0 = seg << 5;
  const float w0 = cw[c * 4 + 0], w1 = cw[c * 4 + 1], w2 = cw[c * 4 + 2], w3 = cw[c * 4 + 3];
  const float bias = cb[c];
  const unsigned short* src = zxb + (size_t)(b << 10) * DPROJ + DINNER + c;
  unsigned short* dstf = xbcf + (size_t)(b << 10) * 128 + c128;
  unsigned short* dstb = xbcb + (size_t)(b << 10) * 128 + c128;
  float r0 = 0.f, r1 = 0.f, r2 = 0.f;
  if (t0 >= 3) {
    r0 = bf2f(src[(size_t)(t0 - 3) * DPROJ]);
    r1 = bf2f(src[(size_t)(t0 - 2) * DPROJ]);
    r2 = bf2f(src[(size_t)(t0 - 1) * DPROJ]);
  }
  for (int s = t0; s < t0 + 32; s++) {
    float x = bf2f(src[(size_t)s * DPROJ]);
    float vf = bias + w0 * r0 + w1 * r1 + w2 * r2 + w3 * x;
    dstf[(size_t)s * 128] = f2bf(silu_f(vf));
    int tp = 1026 - s;
    if (tp <= 1023) {
      float vb = bias + w0 * x + w1 * r2 + w2 * r1 + w3 * r0;
      dstb[(size_t)tp * 128] = f2bf(silu_f(vb));
    }
    r0 = r1; r1 = r2; r2 = x;
  }
  if (seg == 31) {
    float v2 = bias + w1 * r2 + w2 * r1 + w3 * r0;
    float v1 = bias + w2 * r2 + w3 * r1;
    float v0 = bias + w3 * r2;
    dstb[(size_t)2 * 128] = f2bf(silu_f(v2));
    dstb[(size_t)1 * 128] = f2bf(silu_f(v1));
    dstb[0] = f2bf(silu_f(v0));
  }
}

// ---------------- chunked SSD, p-split: 2 blocks per (dir,b,h) ----------------
// Grid 512 = 2 blocks/CU (LDS 62.5KB, __launch_bounds__(512,4)). Block (unit, ph):
// ph selects head-dim half p in [ph*32, ph*32+32). Unlike R7's i-split (which
// duplicated x-conv staging: FETCH +55%, net loss), the p-axis partitions the
// expensive work cleanly: x-conv staging, Y/T outputs, S-state rows, h state and
// the Y store all split by p with ZERO duplication. Duplicated (cheap): dt-scan,
// GEMM1 (4 MFMA/thread), mask pass, Bt staging -- ~25% of per-chunk work.
// GEMM1/T operand fragments (conv'd B/C) are read DIRECTLY from global xbc
// (16B/lane contiguous, L2+XCD-local after swizzle; path validated in R7),
// prefetched 1 chunk ahead in registers -- Cb/Bb LDS dropped.
// Wave roles (8 waves): iw = w>>1 (0..3), sw = w&1 (0..1):
//   GEMM1 tile [iw*16+16][sw*32+32]; mask same; Y/T tile (i=iw*16, p_l=sw*16);
//   S tile (p_l=sw*16 rows, n=iw*16 cols). Accumulation orders identical to R8
//   (kq-sequential) -> bit-identical output.
__global__ __launch_bounds__(512, 4)
void ssd_chunk(const unsigned short* __restrict__ zxb,
               const unsigned short* __restrict__ xbcf, const unsigned short* __restrict__ xbcb,
               const float* __restrict__ cw, const float* __restrict__ cb,
               const float* __restrict__ dtf, const float* __restrict__ dtb,
               const float* __restrict__ A_log, const float* __restrict__ Dp,
               unsigned short* __restrict__ yf, unsigned short* __restrict__ yb) {
  const int blk = xcd_swz(blockIdx.x, 512);
  const int ph = blk & 1;           // p-half
  const int unit = blk >> 1;        // (dir,b,h); both halves + h-group co-XCD
  const int dir = unit >> 7;
  const int b = (unit >> 4) & 7;
  const int h = unit & 15;
  const unsigned short* xbc = dir ? xbcb : xbcf;
  const float* dts = (dir ? dtb : dtf) + ((size_t)((b << 4) + h) << 10);
  unsigned short* yo = dir ? yb : yf;
  const float A = -expf(A_log[h]);
  const float Dh = Dp[h];
  const int tid = threadIdx.x;
  const int lane = tid & 63;
  const int w = tid >> 6;           // 0..7
  const int iw = w >> 1;            // 0..3  (i-block; n-block for S)
  const int sw = w & 1;             // 0..1  (s-half for GEMM1; p-block for Y/T/S)
  const int lrow = lane & 15;
  const int quad = lane >> 4;
  const int lk8 = quad << 3;
  const int bS = b << 10;

  __shared__ unsigned short Xt[2][32 * 72];   // [p_local][s] conv'd x (our half)
  __shared__ unsigned short Bt[2][64 * 72];   // [n][s] transposed, * wv_s
  __shared__ unsigned short Hb[2][32 * 72];   // [p_local][n] h_init
  __shared__ unsigned short Mb[64 * 72];      // [i][s] masked (single buffer)
  __shared__ float sdt_all[1024];
  __shared__ float Lv_all[16][64];
  __shared__ float ev_all[16][64];
  __shared__ float wv_all[16][64];
  __shared__ float dtot_all[16];

  // ---- staging roles ----
  // Bt transpose (full 64 B-channels): pr pairs, sg -> 4 timesteps
  const int pr = tid & 31;
  const int sg = tid >> 5;
  const unsigned short* bvrow = xbc + (size_t)(bS + sg * 4) * 128 + pr * 2;
  // Xt transpose (our 32 x-channels): pr2 pairs (16), sg2 -> 2 timesteps (32 groups)
  const int pr2 = tid & 15;
  const int sg2 = tid >> 4;
  const int ccx = h * 64 + ph * 32 + pr2 * 2;
  const float4 wx0 = *(const float4*)(cw + ccx * 4);
  const float4 wx1 = *(const float4*)(cw + (ccx + 1) * 4);
  const float bx0 = cb[ccx], bx1 = cb[ccx + 1];

  unsigned int bv[4];
  unsigned int xin[5];              // 5 raw zxb rows (2 ch each) for 2 conv outputs
  bf16x8 af[2], bfr[4];             // direct-global frags: C rows (iw), B rows (sw)

  auto frag_load = [&](int c) {
    const unsigned short* base = xbc + (size_t)(bS + c * 64) * 128;
#pragma unroll
    for (int kq = 0; kq < 2; kq++) {
      af[kq] = *(const bf16x8*)(base + (size_t)(iw * 16 + lrow) * 128 + 64 + kq * 32 + lk8);
#pragma unroll
      for (int j = 0; j < 2; j++)
        bfr[j * 2 + kq] =
            *(const bf16x8*)(base + (size_t)(sw * 32 + j * 16 + lrow) * 128 + kq * 32 + lk8);
    }
  };
  auto stage_load = [&](int c) {
    const unsigned short* tp = bvrow + (size_t)c * 64 * 128;
#pragma unroll
    for (int k = 0; k < 4; k++) bv[k] = *(const unsigned int*)(tp + (size_t)k * 128);
    const int li0 = c * 64 + sg2 * 2 - 3;
#pragma unroll
    for (int j = 0; j < 5; j++) {
      const int li = li0 + j;
      const int g = dir ? (1023 - li) : li;
      xin[j] = (g >= 0 && g < 1024)
               ? *(const unsigned int*)(zxb + (size_t)(bS + g) * DPROJ + DINNER + ccx)
               : 0u;
    }
  };
  auto stage_write = [&](int buf, int c) {
    unsigned short b0[4], b1[4];
#pragma unroll
    for (int k = 0; k < 4; k++) {
      const float ws = wv_all[c][sg * 4 + k];
      b0[k] = f2bf(bf2f((unsigned short)(bv[k] & 0xffff)) * ws);
      b1[k] = f2bf(bf2f((unsigned short)(bv[k] >> 16)) * ws);
    }
    *(uint2*)&Bt[buf][(pr * 2 + 0) * 72 + sg * 4] = *(const uint2*)b0;
    *(uint2*)&Bt[buf][(pr * 2 + 1) * 72 + sg * 4] = *(const uint2*)b1;
    float f0[5], f1[5];
#pragma unroll
    for (int j = 0; j < 5; j++) {
      f0[j] = bf2f((unsigned short)(xin[j] & 0xffff));
      f1[j] = bf2f((unsigned short)(xin[j] >> 16));
    }
    unsigned short x0[2], x1[2];
#pragma unroll
    for (int k = 0; k < 2; k++) {
      float v0 = bx0 + wx0.x * f0[k] + wx0.y * f0[k + 1] + wx0.z * f0[k + 2] + wx0.w * f0[k + 3];
      float v1 = bx1 + wx1.x * f1[k] + wx1.y * f1[k + 1] + wx1.z * f1[k + 2] + wx1.w * f1[k + 3];
      x0[k] = f2bf(silu_f(v0));
      x1[k] = f2bf(silu_f(v1));
    }
    *(unsigned int*)&Xt[buf][(pr2 * 2 + 0) * 72 + sg2 * 2] = *(const unsigned int*)x0;
    *(unsigned int*)&Xt[buf][(pr2 * 2 + 1) * 72 + sg2 * 2] = *(const unsigned int*)x1;
  };

  // issue chunk-0 global loads ASAP (no LDS deps)
  frag_load(0);
  stage_load(0);

  // dt -> LDS, zero Hb[0] (32*72 = 2304 shorts = 288 uint4)
  *(float2*)&sdt_all[tid * 2] = *(const float2*)(dts + tid * 2);
  if (tid < 288) {
    uint4 z; z.x = 0u; z.y = 0u; z.z = 0u; z.w = 0u;
    *(uint4*)&Hb[0][tid * 8] = z;
  }
  __syncthreads();

  // ---- per-chunk dt prefix scans, parallel over waves: wave w -> chunks 2w, 2w+1 ----
#pragma unroll
  for (int r = 0; r < 2; r++) {
    const int c = w * 2 + r;
    float dtl = sdt_all[c * 64 + lane];
    float v = dtl;
#pragma unroll
    for (int off = 1; off < 64; off <<= 1) {
      float o = __shfl_up(v, off);
      if (lane >= off) v += o;
    }
    const float Lv = A * v;
    const float LL = __shfl(Lv, 63);
    Lv_all[c][lane] = Lv;
    ev_all[c][lane] = fexp(Lv);
    wv_all[c][lane] = dtl * fexp(LL - Lv);   // in (0, dt]: safe
    if (lane == 0) dtot_all[c] = fexp(LL);
  }
  __syncthreads();

  stage_write(0, 0);
  stage_load(1);
  __syncthreads();

  f32x4 hacc = {0.f, 0.f, 0.f, 0.f};

  int cur = 0;
  for (int c = 0; c < 16; c++) {
    const int t0 = c << 6;

    // GEMM1: M1 tile [iw*16..+16][sw*32..+32] = C @ B^T (frags from global)
    f32x4 m1[2];
#pragma unroll
    for (int j = 0; j < 2; j++) { f32x4 z = {0.f, 0.f, 0.f, 0.f}; m1[j] = z; }
#pragma unroll
    for (int kq = 0; kq < 2; kq++)
#pragma unroll
      for (int j = 0; j < 2; j++)
        m1[j] = __builtin_amdgcn_mfma_f32_16x16x32_bf16(af[kq], bfr[j * 2 + kq], m1[j], 0, 0, 0);
    // mask + decay -> Mb (full [64][64], duplicated across ph -- cheap)
#pragma unroll
    for (int r = 0; r < 4; r++) {
      const int i = iw * 16 + quad * 4 + r;
      const float Li = Lv_all[c][i];
#pragma unroll
      for (int j = 0; j < 2; j++) {
        const int s = sw * 32 + j * 16 + lrow;
        const float Ls = Lv_all[c][s];
        const float ds = sdt_all[c * 64 + s];
        float val = (s <= i) ? m1[j][r] * fexp(Li - Ls) * ds : 0.f;
        Mb[i * 72 + s] = f2bf(val);
      }
    }
    __syncthreads();   // Mb visible (cross-wave columns)

    // set2: Y = M@X [i][p_l] ; T = C@H^T [i][p_l] ; S = Xt@Bt^T [p_l][n]
    f32x4 Y = {0.f, 0.f, 0.f, 0.f};
    f32x4 T = {0.f, 0.f, 0.f, 0.f};
    f32x4 S = {0.f, 0.f, 0.f, 0.f};
    bf16x8 am[2], xp[2];
#pragma unroll
    for (int kq = 0; kq < 2; kq++) {
      am[kq] = *(const bf16x8*)&Mb[(iw * 16 + lrow) * 72 + kq * 32 + lk8];
      xp[kq] = *(const bf16x8*)&Xt[cur][(sw * 16 + lrow) * 72 + kq * 32 + lk8];
    }
#pragma unroll
    for (int kq = 0; kq < 2; kq++) {
      bf16x8 bh = *(const bf16x8*)&Hb[cur][(sw * 16 + lrow) * 72 + kq * 32 + lk8];
      bf16x8 bw = *(const bf16x8*)&Bt[cur][(iw * 16 + lrow) * 72 + kq * 32 + lk8];
      Y = __builtin_amdgcn_mfma_f32_16x16x32_bf16(am[kq], xp[kq], Y, 0, 0, 0);
      T = __builtin_amdgcn_mfma_f32_16x16x32_bf16(af[kq], bh, T, 0, 0, 0);
      S = __builtin_amdgcn_mfma_f32_16x16x32_bf16(xp[kq], bw, S, 0, 0, 0);
    }

    // combine + store Y (bf16), update h
    const float dtot = dtot_all[c];
    const int pl = sw * 16 + lrow;              // local p (0..31)
#pragma unroll
    for (int r = 0; r < 4; r++) {
      const int i = iw * 16 + quad * 4 + r;
      const float ei = ev_all[c][i];
      float yv = Y[r] + ei * T[r] + Dh * bf2f(Xt[cur][pl * 72 + i]);
      yo[(size_t)(bS + t0 + i) * DINNER + h * 64 + ph * 32 + pl] = f2bf(yv);
    }
#pragma unroll
    for (int r = 0; r < 4; r++)
      hacc[r] = dtot * hacc[r] + S[r];

    const int nxt = cur ^ 1;
    if (c + 1 < 16) {
      // h_init for chunk c+1: wave (iw,sw) owns rows sw*16..+16, cols iw*16..+16
#pragma unroll
      for (int r = 0; r < 4; r++)
        Hb[nxt][(sw * 16 + quad * 4 + r) * 72 + iw * 16 + lrow] = f2bf(hacc[r]);
      stage_write(nxt, c + 1);            // regs loaded a full chunk ago -> no stall
      if (c + 2 < 16) stage_load(c + 2);  // in flight across all of chunk c+1
      frag_load(c + 1);                   // af/bfr dead after set2; 1-ahead
    }
    __syncthreads();   // [nxt] staging visible; [cur] reads complete
    cur = nxt;
  }
}

// ---------------- block reduction (256 threads, 4 waves) ----------------
__device__ inline float2 block_sum2_256(float a, float b) {
#pragma unroll
  for (int o = 32; o >= 1; o >>= 1) { a += __shfl_xor(a, o); b += __shfl_xor(b, o); }
  __shared__ float ra[4], rb[4];
  const int lane = threadIdx.x & 63, w = threadIdx.x >> 6;
  if (lane == 0) { ra[w] = a; rb[w] = b; }
  __syncthreads();
  float2 out;
  out.x = ra[0] + ra[1] + ra[2] + ra[3];
  out.y = rb[0] + rb[1] + rb[2] + rb[3];
  return out;
}

// ---------------- combined gate+RMS for BOTH dirs -> comb = gn_f + 0.5*gn_b (bf16) ----
__global__ __launch_bounds__(256)
void gate_rms_comb(const unsigned short* __restrict__ yf, const unsigned short* __restrict__ yb,
                   const unsigned short* __restrict__ zxb, const float* __restrict__ nw,
                   unsigned short* __restrict__ comb) {
  const int bt = blockIdx.x;               // 0..8191 (fwd time == bwd row index)
  const int b = bt >> 10, t = bt & 1023;
  const int zrowb = (b << 10) + (1023 - t);
  const int tid = threadIdx.x;
  ushort4 yf4 = *(const ushort4*)(yf + (size_t)bt * DINNER + tid * 4);
  ushort4 yb4 = *(const ushort4*)(yb + (size_t)bt * DINNER + tid * 4);
  ushort4 zf4 = *(const ushort4*)(zxb + (size_t)bt * DPROJ + tid * 4);
  ushort4 zb4 = *(const ushort4*)(zxb + (size_t)zrowb * DPROJ + tid * 4);
  float gf[4], gb[4];
  gf[0] = bf2f(yf4.x) * silu_f(bf2f(zf4.x));
  gf[1] = bf2f(yf4.y) * silu_f(bf2f(zf4.y));
  gf[2] = bf2f(yf4.z) * silu_f(bf2f(zf4.z));
  gf[3] = bf2f(yf4.w) * silu_f(bf2f(zf4.w));
  gb[0] = bf2f(yb4.x) * silu_f(bf2f(zb4.x));
  gb[1] = bf2f(yb4.y) * silu_f(bf2f(zb4.y));
  gb[2] = bf2f(yb4.z) * silu_f(bf2f(zb4.z));
  gb[3] = bf2f(yb4.w) * silu_f(bf2f(zb4.w));
  float2 sr = block_sum2_256(gf[0]*gf[0] + gf[1]*gf[1] + gf[2]*gf[2] + gf[3]*gf[3],
                             gb[0]*gb[0] + gb[1]*gb[1] + gb[2]*gb[2] + gb[3]*gb[3]);
  float sf = rsqrtf(sr.x * (1.f / 1024.f) + 1e-5f);
  float sb = 0.5f * rsqrtf(sr.y * (1.f / 1024.f) + 1e-5f);
  float4 wv = *(const float4*)(nw + tid * 4);
  unsigned short* o = comb + (size_t)bt * DINNER + tid * 4;
  o[0] = f2bf((gf[0] * sf + gb[0] * sb) * wv.x);
  o[1] = f2bf((gf[1] * sf + gb[1] * sb) * wv.y);
  o[2] = f2bf((gf[2] * sf + gb[2] * sb) * wv.z);
  o[3] = f2bf((gf[3] * sf + gb[3] * sb) * wv.w);
}

// ---------------- h = sum of 2 bf16 partials + u; layernorm -> fp32 + bf16 ----------------
__global__ __launch_bounds__(256)
void combine_ln(const unsigned short* __restrict__ mo, const float* __restrict__ u,
                const float* __restrict__ w, const float* __restrict__ bias,
                float* __restrict__ hln, unsigned short* __restrict__ hbf) {
  const int bt = blockIdx.x;
  const int tid = threadIdx.x;
  const float2 uu = *(const float2*)(u + (size_t)bt * DMODEL + tid * 2);
  float vx = uu.x, vy = uu.y;
#pragma unroll
  for (int z = 0; z < 2; z++) {
    ushort2 p = *(const ushort2*)(mo + (size_t)z * NTOK * DMODEL + (size_t)bt * DMODEL + tid * 2);
    vx += bf2f(p.x);
    vy += bf2f(p.y);
  }
  float2 sr = block_sum2_256(vx + vy, vx * vx + vy * vy);
  float mean = sr.x * (1.f / 512.f);
  float var = sr.y * (1.f / 512.f) - mean * mean;
  float inv = rsqrtf(var + 1e-12f);
  float2 wv = *(const float2*)(w + tid * 2);
  float2 bv = *(const float2*)(bias + tid * 2);
  float ox = (vx - mean) * inv * wv.x + bv.x;
  float oy = (vy - mean) * inv * wv.y + bv.y;
  *(float2*)(hln + (size_t)bt * DMODEL + tid * 2) = make_float2(ox, oy);
  hbf[(size_t)bt * DMODEL + tid * 2] = f2bf(ox);
  hbf[(size_t)bt * DMODEL + tid * 2 + 1] = f2bf(oy);
}

// ---------------- out = layernorm(sum of 2 bf16 partials + b2 + hln) ----------------
__global__ __launch_bounds__(256)
void final_ln(const unsigned short* __restrict__ f2, const float* __restrict__ b2,
              const float* __restrict__ hln,
              const float* __restrict__ w, const float* __restrict__ bias,
              float* __restrict__ outp) {
  const int bt = blockIdx.x;
  const int tid = threadIdx.x;
  const float2 bb = *(const float2*)(b2 + tid * 2);
  const float2 h = *(const float2*)(hln + (size_t)bt * DMODEL + tid * 2);
  float vx = bb.x + h.x;
  float vy = bb.y + h.y;
#pragma unroll
  for (int z = 0; z < 2; z++) {
    ushort2 p = *(const ushort2*)(f2 + (size_t)z * NTOK * DMODEL + (size_t)bt * DMODEL + tid * 2);
    vx += bf2f(p.x);
    vy += bf2f(p.y);
  }
  float2 sr = block_sum2_256(vx + vy, vx * vx + vy * vy);
  float mean = sr.x * (1.f / 512.f);
  float var = sr.y * (1.f / 512.f) - mean * mean;
  float inv = rsqrtf(var + 1e-12f);
  float2 wv = *(const float2*)(w + tid * 2);
  float2 bv = *(const float2*)(bias + tid * 2);
  *(float2*)(outp + (size_t)bt * DMODEL + tid * 2) =
      make_float2((vx - mean) * inv * wv.x + bv.x, (vy - mean) * inv * wv.y + bv.y);
}

extern "C" void kernel_launch(void* const* d_in, const int* in_sizes, int n_in,
                              void* d_out, int out_size, void* d_ws, size_t ws_size,
                              hipStream_t stream) {
  const float* item_emb   = (const float*)d_in[0];
  const float* in_proj_w  = (const float*)d_in[3];
  const float* conv_w     = (const float*)d_in[4];
  const float* conv_b     = (const float*)d_in[5];
  const float* dt_bias    = (const float*)d_in[6];
  const float* A_log      = (const float*)d_in[7];
  const float* Dp         = (const float*)d_in[8];
  const float* norm_w     = (const float*)d_in[9];
  const float* out_proj_w = (const float*)d_in[10];
  const float* ln_w       = (const float*)d_in[11];
  const float* ln_b       = (const float*)d_in[12];
  const float* w1         = (const float*)d_in[13];
  const float* b1         = (const float*)d_in[14];
  const float* w2         = (const float*)d_in[15];
  const float* b2         = (const float*)d_in[16];
  const float* fln_w      = (const float*)d_in[17];
  const float* fln_b      = (const float*)d_in[18];
  float* outp = (float*)d_out;
  char* ws = (char*)d_ws;

  // ---- workspace layout (bytes) ----
  const size_t o_ubf  = 0;                 // [8192,512]  bf16    8,388,608
  const size_t o_win  = 8388608;           // [2304,512]  bf16    2,359,296
  const size_t o_wout = 10747904;          // [512,1024]  bf16    1,048,576
  const size_t o_w1   = 11796480;          // [2048,512]  bf16    2,097,152
  const size_t o_w2   = 13893632;          // [512,2048]  bf16    2,097,152
  const size_t o_dtf  = 15990784;          // [128,1024]  f32       524,288
  const size_t o_dtb  = 16515072;
  const size_t o_zdt  = 17039360;          // [8192,16]   f32       524,288
  const size_t o_zxb  = 17563648;          // [8192,2192] bf16   35,913,728
  const size_t o_xcf  = 53477376;          // (free region; comb aliases it)
  const size_t o_xbcf = 72351744;          // [8192,128]  bf16    2,097,152
  const size_t o_xbcb = 74448896;          // [8192,128]  bf16    2,097,152
  const size_t o_yf   = 91226112;          // [8192,1024] bf16   16,777,216
  const size_t o_yb   = 108003328;         //               end 124,780,544
  // phase-2 aliases (regions dead by the time these are written)
  const size_t o_comb = o_xcf;             // [8192,1024]   bf16
  const size_t o_mo   = o_zxb;             // 2x[8192,512]  bf16 (zxb dead after gate_rms_comb)
  const size_t o_hln  = o_yb;              // [8192,512]    f32  (yb dead after gate_rms_comb)
  const size_t o_hbf  = o_ubf;             // [8192,512]    bf16 (u_bf dead after in-proj)
  const size_t o_h1   = o_xbcf;            // [8192,2048]   bf16 33.6MB (xbc dead after ssd)
  const size_t o_f2   = o_zxb;             // 2x[8192,512]  bf16 (mo dead after combine_ln)

  unsigned short* u_bf  = (unsigned short*)(ws + o_ubf);
  unsigned short* winb  = (unsigned short*)(ws + o_win);
  unsigned short* woutb = (unsigned short*)(ws + o_wout);
  unsigned short* w1b   = (unsigned short*)(ws + o_w1);
  unsigned short* w2b   = (unsigned short*)(ws + o_w2);
  float* dtf = (float*)(ws + o_dtf);
  float* dtb = (float*)(ws + o_dtb);
  float* zdt = (float*)(ws + o_zdt);
  unsigned short* zxb  = (unsigned short*)(ws + o_zxb);
  unsigned short* xbcf = (unsigned short*)(ws + o_xbcf);
  unsigned short* xbcb = (unsigned short*)(ws + o_xbcb);
  unsigned short* yf  = (unsigned short*)(ws + o_yf);
  unsigned short* yb  = (unsigned short*)(ws + o_yb);
  unsigned short* comb = (unsigned short*)(ws + o_comb);
  unsigned short* mo  = (unsigned short*)(ws + o_mo);
  float* hln = (float*)(ws + o_hln);
  unsigned short* hbf = (unsigned short*)(ws + o_hbf);
  unsigned short* h1b = (unsigned short*)(ws + o_h1);
  unsigned short* f2  = (unsigned short*)(ws + o_f2);

  // ---- all bf16 conversions in one launch ----
  {
    int n = NTOK * DMODEL + DPROJP * DMODEL + DMODEL * DINNER + DFFN * DMODEL + DMODEL * DFFN;
    cvt_all<<<(n + 255) / 256, 256, 0, stream>>>(item_emb, in_proj_w, out_proj_w, w1, w2,
                                                 u_bf, winb, woutb, w1b, w2b);
  }

  // ---- in-proj: zxb[8192,2192](bf16) = u @ in_proj_w^T ; dt cols fp32 -> zdt ----
  gemm_bt<2><<<dim3(DPROJP / 128, NTOK / 128), 256, 0, stream>>>(
      u_bf, winb, zxb, nullptr, zdt, DMODEL, DMODEL, DPROJ, 0);

  // ---- dt (softplus) + conv for B/C channels (merged; x-conv fused into ssd) ----
  dt_conv_bc<<<1152, 256, 0, stream>>>(zdt, dt_bias, dtf, dtb,
                                       zxb, conv_w, conv_b, xbcf, xbcb);

  // ---- chunked SSD, p-split: 512 blocks = 2 per (dir,b,h) -> 2 blocks/CU ----
  ssd_chunk<<<512, 512, 0, stream>>>(zxb, xbcf, xbcb, conv_w, conv_b,
                                     dtf, dtb, A_log, Dp, yf, yb);

  // ---- fused gate + RMS + dir-combine -> comb[8192,1024] bf16 ----
  gate_rms_comb<<<NTOK, 256, 0, stream>>>(yf, yb, zxb, norm_w, comb);

  // ---- out-proj: mo = comb @ out_proj_w^T, split-K=2 (bf16 partials) ----
  gemm_bt<3><<<dim3(DMODEL / 128, NTOK / 128, 2), 256, 0, stream>>>(
      comb, woutb, mo, nullptr, nullptr, DINNER / 2, DINNER, DMODEL,
      (size_t)NTOK * DMODEL);

  // ---- combine + first layernorm (sums 2 partials) ----
  combine_ln<<<NTOK, 256, 0, stream>>>(mo, item_emb, ln_w, ln_b, hln, hbf);

  // ---- FFN1: h1 = gelu(hln @ w1^T + b1) -> bf16 ----
  gemm_bt<1><<<dim3(DFFN / 128, NTOK / 128), 256, 0, stream>>>(
      hbf, w1b, h1b, b1, nullptr, DMODEL, DMODEL, DFFN, 0);

  // ---- FFN2: f2 = h1 @ w2^T, split-K=2 (bf16 partials; bias b2 in final_ln) ----
  gemm_bt<3><<<dim3(DMODEL / 128, NTOK / 128, 2), 256, 0, stream>>>(
      h1b, w2b, f2, nullptr, nullptr, DFFN / 2, DFFN, DMODEL,
      (size_t)NTOK * DMODEL);

  // ---- final layernorm (sums 2 partials + b2) -> d_out ----
  final_ln<<<NTOK, 256, 0, stream>>>(f2, b2, hln, fln_w, fln_b, outp);

  (void)in_sizes; (void)n_in; (void)out_size; (void)ws_size;
}

// Round 12
// 317.931 us; speedup vs baseline: 1.0445x; 1.0445x over previous
//
#include <hip/hip_runtime.h>
#include <math.h>

#define SEQ     1024
#define NBATCH  8
#define NTOK    8192        // NBATCH*SEQLEN
#define DMODEL  512
#define DINNER  1024
#define NHEADS  16
#define DPROJ   2192
#define DPROJP  2304        // padded to multiple of 128
#define CONVDIM 1152
#define DFFN    2048

typedef short bf16x8 __attribute__((ext_vector_type(8)));
typedef float f32x4  __attribute__((ext_vector_type(4)));

__device__ inline unsigned short f2bf(float f) {
  union { float f; unsigned int u; } v; v.f = f;
  unsigned int u = v.u;
  return (unsigned short)((u + 0x7FFFu + ((u >> 16) & 1u)) >> 16);
}
__device__ inline float bf2f(unsigned short s) {
  union { unsigned int u; float f; } v; v.u = ((unsigned int)s) << 16;
  return v.f;
}

// fast transcendentals: native v_exp_f32 / v_rcp_f32 (~1e-7 rel err, far below
// the bf16 rounding these values feed into; ocml expf/erff are 25-60 instr).
__device__ inline float fexp(float x) { return __expf(x); }
__device__ inline float frcp(float x) { return __builtin_amdgcn_rcpf(x); }
__device__ inline float silu_f(float v) { return v * frcp(1.f + fexp(-v)); }
// erf via Abramowitz-Stegun 7.1.26, |err| <= 1.5e-7
__device__ inline float gelu_f(float v) {
  float x = v * 0.7071067811865476f;
  float ax = fabsf(x);
  float t = frcp(1.f + 0.3275911f * ax);
  float p = ((((1.061405429f * t - 1.453152027f) * t + 1.421413741f) * t
              - 0.284496736f) * t + 0.254829592f) * t;
  float er = copysignf(1.f - p * fexp(-ax * ax), x);
  return 0.5f * v * (1.f + er);
}

// XCD-aware swizzle (T1): consecutive HW-dispatched blocks round-robin the 8
// XCDs; remap so each XCD owns a CONTIGUOUS tile range (operand-panel L2 reuse).
// Bijective transpose of the 8 x (nwg/8) id matrix; requires nwg % 8 == 0
// (true for every launch here). R10 verified: ssd FETCH 40.9 -> 19.9 MB.
__device__ inline int xcd_swz(int flat, int nwg) {
  return (flat & 7) * (nwg >> 3) + (flat >> 3);
}

// async global->LDS, 16B per lane; lds base must be wave-uniform (lane*16 added by HW)
#define GLDS16(g, l)                                                         \
  __builtin_amdgcn_global_load_lds(                                          \
      (const __attribute__((address_space(1))) unsigned int*)(g),            \
      (__attribute__((address_space(3))) unsigned int*)(l), 16, 0, 0)

// ---------------- ALL bf16 conversions in ONE launch ----------------
__global__ __launch_bounds__(256)
void cvt_all(const float* __restrict__ u, const float* __restrict__ inw,
             const float* __restrict__ outw, const float* __restrict__ w1,
             const float* __restrict__ w2,
             unsigned short* __restrict__ u_bf, unsigned short* __restrict__ winb,
             unsigned short* __restrict__ woutb, unsigned short* __restrict__ w1b,
             unsigned short* __restrict__ w2b) {
  int i = blockIdx.x * 256 + threadIdx.x;
  const int nu = NTOK * DMODEL;
  const int n0 = DPROJP * DMODEL;
  const int n1 = DMODEL * DINNER;
  const int n2 = DFFN * DMODEL;
  const int n3 = DMODEL * DFFN;
  if (i < nu) {
    u_bf[i] = f2bf(u[i]);
  } else if ((i -= nu) < n0) {
    int r = i / DMODEL;
    winb[i] = (r < DPROJ) ? f2bf(inw[i]) : (unsigned short)0;
  } else if ((i -= n0) < n1) {
    woutb[i] = f2bf(outw[i]);
  } else if ((i -= n1) < n2) {
    w1b[i] = f2bf(w1[i]);
  } else if ((i -= n2) < n3) {
    w2b[i] = f2bf(w2[i]);
  }
}

// ---------------- bf16 MFMA GEMM: C[M,N] = A[M,K] @ B[N,K]^T ----------------
// 128x128 tile, 2x2 waves of 64x64, single-barrier double-buffered GLDS pipeline.
// (R1-proven structure; R2/R3/R4 restructurings all timed-equal or worse.)
// XCD swizzle: blocks sharing an A-panel (same by) land on the same XCD's L2.
// MODE 0: fp32 (+bias). MODE 1: bias+gelu->bf16. MODE 2: bf16, cols>=2176 also
// fp32 -> aux. MODE 3: bf16 PARTIAL at (ushort*)Cout + z*zstrideC (consumer sums).
template <int MODE>
__global__ __launch_bounds__(256)
void gemm_bt(const unsigned short* __restrict__ A, const unsigned short* __restrict__ B,
             void* __restrict__ Cout, const float* __restrict__ bias,
             float* __restrict__ aux, int Ksub, int lda, int Nreal, size_t zstrideC) {
  __shared__ unsigned short sA[2][128 * 32];
  __shared__ unsigned short sB[2][128 * 32];
  const int tid = threadIdx.x;
  // XCD-aware flat-id remap (all grids here have nwg % 8 == 0)
  const int nwg = gridDim.x * gridDim.y * gridDim.z;
  const int flat = blockIdx.x + gridDim.x * (blockIdx.y + gridDim.y * blockIdx.z);
  const int swz = xcd_swz(flat, nwg);
  const int bx = swz % gridDim.x;
  const int tmp = swz / gridDim.x;
  const int by = tmp % gridDim.y;
  const int bz = tmp / gridDim.y;
  const int lane = tid & 63;
  const int wave = tid >> 6;
  const int wm = wave >> 1, wn = wave & 1;
  const int arow = tid >> 2;               // 0..63
  const int acol = (tid & 3) << 3;

  const unsigned short* pA = A + (size_t)(by * 128 + arow) * lda + bz * Ksub + acol;
  const unsigned short* pB = B + (size_t)(bx * 128 + arow) * lda + bz * Ksub + acol;
  const size_t stride64 = (size_t)64 * lda;
  char* sAw[2] = { (char*)&sA[0][0] + wave * 1024, (char*)&sA[1][0] + wave * 1024 };
  char* sBw[2] = { (char*)&sB[0][0] + wave * 1024, (char*)&sB[1][0] + wave * 1024 };

  f32x4 acc[4][4];
#pragma unroll
  for (int i = 0; i < 4; i++)
#pragma unroll
    for (int j = 0; j < 4; j++) { f32x4 z = {0.f, 0.f, 0.f, 0.f}; acc[i][j] = z; }

  // prologue: stage k0=0 into buf 0
  GLDS16(pA, sAw[0]);
  GLDS16(pA + stride64, sAw[0] + 4096);
  GLDS16(pB, sBw[0]);
  GLDS16(pB + stride64, sBw[0] + 4096);
  pA += 32; pB += 32;
  __syncthreads();

  const int lrow = lane & 15;
  const int lkq = (lane >> 4) << 3;
  int cur = 0;
  for (int k0 = 0; k0 < Ksub; k0 += 32) {
    if (k0 + 32 < Ksub) {
      const int nxt = cur ^ 1;
      GLDS16(pA, sAw[nxt]);
      GLDS16(pA + stride64, sAw[nxt] + 4096);
      GLDS16(pB, sBw[nxt]);
      GLDS16(pB + stride64, sBw[nxt] + 4096);
      pA += 32; pB += 32;
    }
    bf16x8 af[4], bfr[4];
#pragma unroll
    for (int mi = 0; mi < 4; mi++)
      af[mi] = *(const bf16x8*)&sA[cur][(wm * 64 + mi * 16 + lrow) * 32 + lkq];
#pragma unroll
    for (int ni = 0; ni < 4; ni++)
      bfr[ni] = *(const bf16x8*)&sB[cur][(wn * 64 + ni * 16 + lrow) * 32 + lkq];
#pragma unroll
    for (int mi = 0; mi < 4; mi++)
#pragma unroll
      for (int ni = 0; ni < 4; ni++)
        acc[mi][ni] = __builtin_amdgcn_mfma_f32_16x16x32_bf16(af[mi], bfr[ni], acc[mi][ni], 0, 0, 0);
    __syncthreads();
    cur ^= 1;
  }

  const int row0 = by * 128 + wm * 64;
  const int col0 = bx * 128 + wn * 64;
  float* outf = (float*)Cout;
  unsigned short* outp16 = (unsigned short*)Cout + (size_t)bz * zstrideC;
#pragma unroll
  for (int mi = 0; mi < 4; mi++) {
#pragma unroll
    for (int ni = 0; ni < 4; ni++) {
      const int col = col0 + ni * 16 + lrow;
      if (col < Nreal) {
        const float bval = (MODE == 0 || MODE == 1) && bias ? bias[col] : 0.f;
#pragma unroll
        for (int r = 0; r < 4; r++) {
          const int row = row0 + mi * 16 + ((lane >> 4) << 2) + r;
          float v = acc[mi][ni][r] + bval;
          if (MODE == 1) {
            ((unsigned short*)Cout)[(size_t)row * Nreal + col] = f2bf(gelu_f(v));
          } else if (MODE == 2) {
            ((unsigned short*)Cout)[(size_t)row * Nreal + col] = f2bf(v);
            if (col >= 2176) aux[(size_t)row * 16 + (col - 2176)] = v;
          } else if (MODE == 3) {
            outp16[(size_t)row * Nreal + col] = f2bf(v);
          } else {
            outf[(size_t)row * Nreal + col] = v;
          }
        }
      }
    }
  }
}

// ---------------- merged: dt softplus (blocks 0..1023) + B/C conv (blocks 1024..1151) ----
__global__ __launch_bounds__(256)
void dt_conv_bc(const float* __restrict__ zdt, const float* __restrict__ dt_bias,
                float* __restrict__ dtf, float* __restrict__ dtb,
                const unsigned short* __restrict__ zxb, const float* __restrict__ cw,
                const float* __restrict__ cb,
                unsigned short* __restrict__ xbcf, unsigned short* __restrict__ xbcb) {
  const int tid = threadIdx.x;
  if (blockIdx.x < 1024) {
    // dt = softplus(zdt + dt_bias); layout [dir][(b*16+h)][t]
    int i = blockIdx.x * 256 + tid;             // 0 .. 262143
    int dir = i >> 17;
    int rem = i & 131071;
    int row = rem >> 10;                        // b*16+h
    int t = rem & 1023;
    int b = row >> 4, h = row & 15;
    int srow = (b << 10) + (dir ? (1023 - t) : t);
    float v = zdt[(size_t)srow * 16 + h] + dt_bias[h];
    float dt = (v > 20.f) ? v : log1pf(fexp(v));
    (dir ? dtb : dtf)[(row << 10) + t] = dt;
    return;
  }
  // conv+silu for B/C channels (128 ch), both dirs; xbc[row][128]
  const int bid = blockIdx.x - 1024;            // 0..127
  const int sx = bid & 15, b = bid >> 4;
  const int c128 = tid & 127;
  const int c = 1024 + c128;
  const int seg = sx * 2 + (tid >> 7);          // 0..31
  const int t0 = seg << 5;
  const float w0 = cw[c * 4 + 0], w1 = cw[c * 4 + 1], w2 = cw[c * 4 + 2], w3 = cw[c * 4 + 3];
  const float bias = cb[c];
  const unsigned short* src = zxb + (size_t)(b << 10) * DPROJ + DINNER + c;
  unsigned short* dstf = xbcf + (size_t)(b << 10) * 128 + c128;
  unsigned short* dstb = xbcb + (size_t)(b << 10) * 128 + c128;
  float r0 = 0.f, r1 = 0.f, r2 = 0.f;
  if (t0 >= 3) {
    r0 = bf2f(src[(size_t)(t0 - 3) * DPROJ]);
    r1 = bf2f(src[(size_t)(t0 - 2) * DPROJ]);
    r2 = bf2f(src[(size_t)(t0 - 1) * DPROJ]);
  }
  for (int s = t0; s < t0 + 32; s++) {
    float x = bf2f(src[(size_t)s * DPROJ]);
    float vf = bias + w0 * r0 + w1 * r1 + w2 * r2 + w3 * x;
    dstf[(size_t)s * 128] = f2bf(silu_f(vf));
    int tp = 1026 - s;
    if (tp <= 1023) {
      float vb = bias + w0 * x + w1 * r2 + w2 * r1 + w3 * r0;
      dstb[(size_t)tp * 128] = f2bf(silu_f(vb));
    }
    r0 = r1; r1 = r2; r2 = x;
  }
  if (seg == 31) {
    float v2 = bias + w1 * r2 + w2 * r1 + w3 * r0;
    float v1 = bias + w2 * r2 + w3 * r1;
    float v0 = bias + w3 * r2;
    dstb[(size_t)2 * 128] = f2bf(silu_f(v2));
    dstb[(size_t)1 * 128] = f2bf(silu_f(v1));
    dstb[0] = f2bf(silu_f(v0));
  }
}

// ---------------- chunked SSD with FUSED x-channel conv (R10-proven version) ----------------
// One block per (dir,b,h); 512 threads = 8 waves; 16 chunks of L=64.
// x computed in-register from raw zxb rows (4-tap conv + silu), no xcf round-trip.
// XCD swizzle: the 16 h-blocks of one (dir,b) share xbc rows + the zxb row-window
// (R10: FETCH 40.9 -> 19.9 MB).
// R7 i-split and R11 p-split both REGRESSED: any split below the (dir,b,h) unit
// replicates staging/mask/Bt work (+47% VALU cycles in R11) and cancels the TLP
// gain. This granularity is the floor for this decomposition.
__global__ __launch_bounds__(512)
void ssd_chunk(const unsigned short* __restrict__ zxb,
               const unsigned short* __restrict__ xbcf, const unsigned short* __restrict__ xbcb,
               const float* __restrict__ cw, const float* __restrict__ cb,
               const float* __restrict__ dtf, const float* __restrict__ dtb,
               const float* __restrict__ A_log, const float* __restrict__ Dp,
               unsigned short* __restrict__ yf, unsigned short* __restrict__ yb) {
  const int blk = xcd_swz(blockIdx.x, 256);
  const int dir = blk >> 7;
  const int b = (blk >> 4) & 7;
  const int h = blk & 15;
  const unsigned short* xbc = dir ? xbcb : xbcf;
  const float* dts = (dir ? dtb : dtf) + ((size_t)((b << 4) + h) << 10);
  unsigned short* yo = dir ? yb : yf;
  const float A = -expf(A_log[h]);
  const float Dh = Dp[h];
  const int tid = threadIdx.x;
  const int lane = tid & 63;
  const int w = tid >> 6;           // 0..7
  const int wm = w >> 1;            // 0..3
  const int wn = w & 1;             // 0..1
  const int lrow = lane & 15;
  const int quad = lane >> 4;
  const int lk8 = quad << 3;
  const int bS = b << 10;

  __shared__ unsigned short Cb[2][64 * 72];   // [s][n] raw
  __shared__ unsigned short Bb[2][64 * 72];   // [s][n] raw
  __shared__ unsigned short Xt[2][64 * 72];   // [p][s] transposed (conv'd x)
  __shared__ unsigned short Bt[2][64 * 72];   // [n][s] transposed, * wv_s
  __shared__ unsigned short Hb[2][64 * 72];   // [p][n] h_init
  __shared__ unsigned short Mb[64 * 72];      // [i][s] masked (single buffer)
  __shared__ float sdt_all[1024];
  __shared__ float Lv_all[16][64];
  __shared__ float ev_all[16][64];
  __shared__ float wv_all[16][64];
  __shared__ float dtot_all[16];

  // ---- staging roles ----
  const unsigned short* bcrow = xbc + (size_t)(bS + (tid >> 3)) * 128 + (tid & 7) * 8;
  const int pr = tid & 31;
  const int sg = tid >> 5;
  const int ccx = h * 64 + pr * 2;            // this thread's 2 x conv-channels
  const unsigned short* bvrow = xbc + (size_t)(bS + sg * 4) * 128 + pr * 2;
  const float4 wx0 = *(const float4*)(cw + ccx * 4);
  const float4 wx1 = *(const float4*)(cw + (ccx + 1) * 4);
  const float bx0 = cb[ccx], bx1 = cb[ccx + 1];

  uint4 vb, vc;
  unsigned int bv[4];
  unsigned int xin[7];              // 7 raw zxb rows (2 ch each) for the 4-tap window

  auto stage_load = [&](int c) {
    const unsigned short* rp = bcrow + (size_t)c * 64 * 128;
    vb = *(const uint4*)(rp);
    vc = *(const uint4*)(rp + 64);
    const unsigned short* tp = bvrow + (size_t)c * 64 * 128;
#pragma unroll
    for (int k = 0; k < 4; k++) bv[k] = *(const unsigned int*)(tp + (size_t)k * 128);
    const int li0 = c * 64 + sg * 4 - 3;
#pragma unroll
    for (int j = 0; j < 7; j++) {
      const int li = li0 + j;
      const int g = dir ? (1023 - li) : li;
      xin[j] = (g >= 0 && g < 1024)
               ? *(const unsigned int*)(zxb + (size_t)(bS + g) * DPROJ + DINNER + ccx)
               : 0u;
    }
  };

  auto stage_write = [&](int buf, int c) {
    *(uint4*)&Bb[buf][(tid >> 3) * 72 + (tid & 7) * 8] = vb;
    *(uint4*)&Cb[buf][(tid >> 3) * 72 + (tid & 7) * 8] = vc;
    float f0[7], f1[7];
#pragma unroll
    for (int j = 0; j < 7; j++) {
      f0[j] = bf2f((unsigned short)(xin[j] & 0xffff));
      f1[j] = bf2f((unsigned short)(xin[j] >> 16));
    }
    unsigned short x0[4], x1[4], b0[4], b1[4];
#pragma unroll
    for (int k = 0; k < 4; k++) {
      const float ws = wv_all[c][sg * 4 + k];
      float v0 = bx0 + wx0.x * f0[k] + wx0.y * f0[k + 1] + wx0.z * f0[k + 2] + wx0.w * f0[k + 3];
      float v1 = bx1 + wx1.x * f1[k] + wx1.y * f1[k + 1] + wx1.z * f1[k + 2] + wx1.w * f1[k + 3];
      x0[k] = f2bf(silu_f(v0));
      x1[k] = f2bf(silu_f(v1));
      b0[k] = f2bf(bf2f((unsigned short)(bv[k] & 0xffff)) * ws);
      b1[k] = f2bf(bf2f((unsigned short)(bv[k] >> 16)) * ws);
    }
    *(uint2*)&Xt[buf][(pr * 2 + 0) * 72 + sg * 4] = *(const uint2*)x0;
    *(uint2*)&Xt[buf][(pr * 2 + 1) * 72 + sg * 4] = *(const uint2*)x1;
    *(uint2*)&Bt[buf][(pr * 2 + 0) * 72 + sg * 4] = *(const uint2*)b0;
    *(uint2*)&Bt[buf][(pr * 2 + 1) * 72 + sg * 4] = *(const uint2*)b1;
  };

  // issue chunk-0 global loads ASAP (no LDS deps)
  stage_load(0);

  // dt -> LDS, zero Hb[0]
  *(float2*)&sdt_all[tid * 2] = *(const float2*)(dts + tid * 2);
  {
    uint4 z; z.x = 0u; z.y = 0u; z.z = 0u; z.w = 0u;
    *(uint4*)&Hb[0][(tid >> 3) * 72 + (tid & 7) * 8] = z;
  }
  __syncthreads();

  // ---- per-chunk dt prefix scans, parallel over waves: wave w -> chunks 2w, 2w+1 ----
#pragma unroll
  for (int r = 0; r < 2; r++) {
    const int c = w * 2 + r;
    float dtl = sdt_all[c * 64 + lane];
    float v = dtl;
#pragma unroll
    for (int off = 1; off < 64; off <<= 1) {
      float o = __shfl_up(v, off);
      if (lane >= off) v += o;
    }
    const float Lv = A * v;
    const float LL = __shfl(Lv, 63);
    Lv_all[c][lane] = Lv;
    ev_all[c][lane] = fexp(Lv);
    wv_all[c][lane] = dtl * fexp(LL - Lv);   // in (0, dt]: safe
    if (lane == 0) dtot_all[c] = fexp(LL);
  }
  __syncthreads();

  stage_write(0, 0);
  stage_load(1);
  __syncthreads();

  f32x4 hacc[2];
#pragma unroll
  for (int j = 0; j < 2; j++) { f32x4 z = {0.f, 0.f, 0.f, 0.f}; hacc[j] = z; }

  int cur = 0;
  for (int c = 0; c < 16; c++) {
    const int t0 = c << 6;

    // GEMM1: M1[i][s] = C @ B^T (raw, over n)
    f32x4 m1[2];
#pragma unroll
    for (int j = 0; j < 2; j++) { f32x4 z = {0.f, 0.f, 0.f, 0.f}; m1[j] = z; }
#pragma unroll
    for (int kq = 0; kq < 2; kq++) {
      bf16x8 af = *(const bf16x8*)&Cb[cur][(wm * 16 + lrow) * 72 + kq * 32 + lk8];
#pragma unroll
      for (int j = 0; j < 2; j++) {
        bf16x8 bf = *(const bf16x8*)&Bb[cur][(wn * 32 + j * 16 + lrow) * 72 + kq * 32 + lk8];
        m1[j] = __builtin_amdgcn_mfma_f32_16x16x32_bf16(af, bf, m1[j], 0, 0, 0);
      }
    }
    // mask + decay -> Mb (scan values from LDS, no shfl)
#pragma unroll
    for (int r = 0; r < 4; r++) {
      const int i = wm * 16 + quad * 4 + r;
      const float Li = Lv_all[c][i];
#pragma unroll
      for (int j = 0; j < 2; j++) {
        const int s = wn * 32 + j * 16 + lrow;
        const float Ls = Lv_all[c][s];
        const float ds = sdt_all[c * 64 + s];
        float val = (s <= i) ? m1[j][r] * fexp(Li - Ls) * ds : 0.f;
        Mb[i * 72 + s] = f2bf(val);
      }
    }
    __syncthreads();   // Mb visible (cross-wave columns)

    // Y = M@X ; T = C@H^T ; S = Xt@Bt^T  (Bt already carries wv_s)
    f32x4 Y[2], T[2], S[2];
#pragma unroll
    for (int j = 0; j < 2; j++) {
      f32x4 z = {0.f, 0.f, 0.f, 0.f};
      Y[j] = z; T[j] = z; S[j] = z;
    }
#pragma unroll
    for (int kq = 0; kq < 2; kq++) {
      bf16x8 am = *(const bf16x8*)&Mb[(wm * 16 + lrow) * 72 + kq * 32 + lk8];
      bf16x8 ac = *(const bf16x8*)&Cb[cur][(wm * 16 + lrow) * 72 + kq * 32 + lk8];
      bf16x8 ax = *(const bf16x8*)&Xt[cur][(wm * 16 + lrow) * 72 + kq * 32 + lk8];
#pragma unroll
      for (int j = 0; j < 2; j++) {
        const int brow = (wn * 32 + j * 16 + lrow) * 72 + kq * 32 + lk8;
        bf16x8 bx = *(const bf16x8*)&Xt[cur][brow];
        bf16x8 bh = *(const bf16x8*)&Hb[cur][brow];
        bf16x8 bw = *(const bf16x8*)&Bt[cur][brow];
        Y[j] = __builtin_amdgcn_mfma_f32_16x16x32_bf16(am, bx, Y[j], 0, 0, 0);
        T[j] = __builtin_amdgcn_mfma_f32_16x16x32_bf16(ac, bh, T[j], 0, 0, 0);
        S[j] = __builtin_amdgcn_mfma_f32_16x16x32_bf16(ax, bw, S[j], 0, 0, 0);
      }
    }

    // combine + store Y (bf16), update h
    const float dtot = dtot_all[c];
#pragma unroll
    for (int r = 0; r < 4; r++) {
      const int i = wm * 16 + quad * 4 + r;
      const float ei = ev_all[c][i];
#pragma unroll
      for (int j = 0; j < 2; j++) {
        const int p = wn * 32 + j * 16 + lrow;
        float yv = Y[j][r] + ei * T[j][r] + Dh * bf2f(Xt[cur][p * 72 + i]);
        yo[(size_t)(bS + t0 + i) * DINNER + h * 64 + p] = f2bf(yv);
      }
    }
#pragma unroll
    for (int j = 0; j < 2; j++)
#pragma unroll
      for (int r = 0; r < 4; r++)
        hacc[j][r] = dtot * hacc[j][r] + S[j][r];

    const int nxt = cur ^ 1;
    if (c + 1 < 16) {
      // h_init for chunk c+1
#pragma unroll
      for (int j = 0; j < 2; j++)
#pragma unroll
        for (int r = 0; r < 4; r++)
          Hb[nxt][(wm * 16 + quad * 4 + r) * 72 + wn * 32 + j * 16 + lrow] = f2bf(hacc[j][r]);
      stage_write(nxt, c + 1);            // regs loaded a full chunk ago -> no stall
      if (c + 2 < 16) stage_load(c + 2);  // in flight across all of chunk c+1
    }
    __syncthreads();   // [nxt] staging visible; [cur] reads complete
    cur = nxt;
  }
}

// ---------------- block reduction (256 threads, 4 waves) ----------------
__device__ inline float2 block_sum2_256(float a, float b) {
#pragma unroll
  for (int o = 32; o >= 1; o >>= 1) { a += __shfl_xor(a, o); b += __shfl_xor(b, o); }
  __shared__ float ra[4], rb[4];
  const int lane = threadIdx.x & 63, w = threadIdx.x >> 6;
  if (lane == 0) { ra[w] = a; rb[w] = b; }
  __syncthreads();
  float2 out;
  out.x = ra[0] + ra[1] + ra[2] + ra[3];
  out.y = rb[0] + rb[1] + rb[2] + rb[3];
  return out;
}

// ---------------- combined gate+RMS for BOTH dirs -> comb = gn_f + 0.5*gn_b (bf16) ----
__global__ __launch_bounds__(256)
void gate_rms_comb(const unsigned short* __restrict__ yf, const unsigned short* __restrict__ yb,
                   const unsigned short* __restrict__ zxb, const float* __restrict__ nw,
                   unsigned short* __restrict__ comb) {
  const int bt = blockIdx.x;               // 0..8191 (fwd time == bwd row index)
  const int b = bt >> 10, t = bt & 1023;
  const int zrowb = (b << 10) + (1023 - t);
  const int tid = threadIdx.x;
  ushort4 yf4 = *(const ushort4*)(yf + (size_t)bt * DINNER + tid * 4);
  ushort4 yb4 = *(const ushort4*)(yb + (size_t)bt * DINNER + tid * 4);
  ushort4 zf4 = *(const ushort4*)(zxb + (size_t)bt * DPROJ + tid * 4);
  ushort4 zb4 = *(const ushort4*)(zxb + (size_t)zrowb * DPROJ + tid * 4);
  float gf[4], gb[4];
  gf[0] = bf2f(yf4.x) * silu_f(bf2f(zf4.x));
  gf[1] = bf2f(yf4.y) * silu_f(bf2f(zf4.y));
  gf[2] = bf2f(yf4.z) * silu_f(bf2f(zf4.z));
  gf[3] = bf2f(yf4.w) * silu_f(bf2f(zf4.w));
  gb[0] = bf2f(yb4.x) * silu_f(bf2f(zb4.x));
  gb[1] = bf2f(yb4.y) * silu_f(bf2f(zb4.y));
  gb[2] = bf2f(yb4.z) * silu_f(bf2f(zb4.z));
  gb[3] = bf2f(yb4.w) * silu_f(bf2f(zb4.w));
  float2 sr = block_sum2_256(gf[0]*gf[0] + gf[1]*gf[1] + gf[2]*gf[2] + gf[3]*gf[3],
                             gb[0]*gb[0] + gb[1]*gb[1] + gb[2]*gb[2] + gb[3]*gb[3]);
  float sf = rsqrtf(sr.x * (1.f / 1024.f) + 1e-5f);
  float sb = 0.5f * rsqrtf(sr.y * (1.f / 1024.f) + 1e-5f);
  float4 wv = *(const float4*)(nw + tid * 4);
  unsigned short* o = comb + (size_t)bt * DINNER + tid * 4;
  o[0] = f2bf((gf[0] * sf + gb[0] * sb) * wv.x);
  o[1] = f2bf((gf[1] * sf + gb[1] * sb) * wv.y);
  o[2] = f2bf((gf[2] * sf + gb[2] * sb) * wv.z);
  o[3] = f2bf((gf[3] * sf + gb[3] * sb) * wv.w);
}

// ---------------- h = sum of 2 bf16 partials + u; layernorm -> fp32 + bf16 ----------------
__global__ __launch_bounds__(256)
void combine_ln(const unsigned short* __restrict__ mo, const float* __restrict__ u,
                const float* __restrict__ w, const float* __restrict__ bias,
                float* __restrict__ hln, unsigned short* __restrict__ hbf) {
  const int bt = blockIdx.x;
  const int tid = threadIdx.x;
  const float2 uu = *(const float2*)(u + (size_t)bt * DMODEL + tid * 2);
  float vx = uu.x, vy = uu.y;
#pragma unroll
  for (int z = 0; z < 2; z++) {
    ushort2 p = *(const ushort2*)(mo + (size_t)z * NTOK * DMODEL + (size_t)bt * DMODEL + tid * 2);
    vx += bf2f(p.x);
    vy += bf2f(p.y);
  }
  float2 sr = block_sum2_256(vx + vy, vx * vx + vy * vy);
  float mean = sr.x * (1.f / 512.f);
  float var = sr.y * (1.f / 512.f) - mean * mean;
  float inv = rsqrtf(var + 1e-12f);
  float2 wv = *(const float2*)(w + tid * 2);
  float2 bv = *(const float2*)(bias + tid * 2);
  float ox = (vx - mean) * inv * wv.x + bv.x;
  float oy = (vy - mean) * inv * wv.y + bv.y;
  *(float2*)(hln + (size_t)bt * DMODEL + tid * 2) = make_float2(ox, oy);
  hbf[(size_t)bt * DMODEL + tid * 2] = f2bf(ox);
  hbf[(size_t)bt * DMODEL + tid * 2 + 1] = f2bf(oy);
}

// ---------------- out = layernorm(sum of 2 bf16 partials + b2 + hln) ----------------
__global__ __launch_bounds__(256)
void final_ln(const unsigned short* __restrict__ f2, const float* __restrict__ b2,
              const float* __restrict__ hln,
              const float* __restrict__ w, const float* __restrict__ bias,
              float* __restrict__ outp) {
  const int bt = blockIdx.x;
  const int tid = threadIdx.x;
  const float2 bb = *(const float2*)(b2 + tid * 2);
  const float2 h = *(const float2*)(hln + (size_t)bt * DMODEL + tid * 2);
  float vx = bb.x + h.x;
  float vy = bb.y + h.y;
#pragma unroll
  for (int z = 0; z < 2; z++) {
    ushort2 p = *(const ushort2*)(f2 + (size_t)z * NTOK * DMODEL + (size_t)bt * DMODEL + tid * 2);
    vx += bf2f(p.x);
    vy += bf2f(p.y);
  }
  float2 sr = block_sum2_256(vx + vy, vx * vx + vy * vy);
  float mean = sr.x * (1.f / 512.f);
  float var = sr.y * (1.f / 512.f) - mean * mean;
  float inv = rsqrtf(var + 1e-12f);
  float2 wv = *(const float2*)(w + tid * 2);
  float2 bv = *(const float2*)(bias + tid * 2);
  *(float2*)(outp + (size_t)bt * DMODEL + tid * 2) =
      make_float2((vx - mean) * inv * wv.x + bv.x, (vy - mean) * inv * wv.y + bv.y);
}

extern "C" void kernel_launch(void* const* d_in, const int* in_sizes, int n_in,
                              void* d_out, int out_size, void* d_ws, size_t ws_size,
                              hipStream_t stream) {
  const float* item_emb   = (const float*)d_in[0];
  const float* in_proj_w  = (const float*)d_in[3];
  const float* conv_w     = (const float*)d_in[4];
  const float* conv_b     = (const float*)d_in[5];
  const float* dt_bias    = (const float*)d_in[6];
  const float* A_log      = (const float*)d_in[7];
  const float* Dp         = (const float*)d_in[8];
  const float* norm_w     = (const float*)d_in[9];
  const float* out_proj_w = (const float*)d_in[10];
  const float* ln_w       = (const float*)d_in[11];
  const float* ln_b       = (const float*)d_in[12];
  const float* w1         = (const float*)d_in[13];
  const float* b1         = (const float*)d_in[14];
  const float* w2         = (const float*)d_in[15];
  const float* b2         = (const float*)d_in[16];
  const float* fln_w      = (const float*)d_in[17];
  const float* fln_b      = (const float*)d_in[18];
  float* outp = (float*)d_out;
  char* ws = (char*)d_ws;

  // ---- workspace layout (bytes) ----
  const size_t o_ubf  = 0;                 // [8192,512]  bf16    8,388,608
  const size_t o_win  = 8388608;           // [2304,512]  bf16    2,359,296
  const size_t o_wout = 10747904;          // [512,1024]  bf16    1,048,576
  const size_t o_w1   = 11796480;          // [2048,512]  bf16    2,097,152
  const size_t o_w2   = 13893632;          // [512,2048]  bf16    2,097,152
  const size_t o_dtf  = 15990784;          // [128,1024]  f32       524,288
  const size_t o_dtb  = 16515072;
  const size_t o_zdt  = 17039360;          // [8192,16]   f32       524,288
  const size_t o_zxb  = 17563648;          // [8192,2192] bf16   35,913,728
  const size_t o_xcf  = 53477376;          // (free region; comb aliases it)
  const size_t o_xbcf = 72351744;          // [8192,128]  bf16    2,097,152
  const size_t o_xbcb = 74448896;          // [8192,128]  bf16    2,097,152
  const size_t o_yf   = 91226112;          // [8192,1024] bf16   16,777,216
  const size_t o_yb   = 108003328;         //               end 124,780,544
  // phase-2 aliases (regions dead by the time these are written)
  const size_t o_comb = o_xcf;             // [8192,1024]   bf16
  const size_t o_mo   = o_zxb;             // 2x[8192,512]  bf16 (zxb dead after gate_rms_comb)
  const size_t o_hln  = o_yb;              // [8192,512]    f32  (yb dead after gate_rms_comb)
  const size_t o_hbf  = o_ubf;             // [8192,512]    bf16 (u_bf dead after in-proj)
  const size_t o_h1   = o_xbcf;            // [8192,2048]   bf16 33.6MB (xbc dead after ssd)
  const size_t o_f2   = o_zxb;             // 2x[8192,512]  bf16 (mo dead after combine_ln)

  unsigned short* u_bf  = (unsigned short*)(ws + o_ubf);
  unsigned short* winb  = (unsigned short*)(ws + o_win);
  unsigned short* woutb = (unsigned short*)(ws + o_wout);
  unsigned short* w1b   = (unsigned short*)(ws + o_w1);
  unsigned short* w2b   = (unsigned short*)(ws + o_w2);
  float* dtf = (float*)(ws + o_dtf);
  float* dtb = (float*)(ws + o_dtb);
  float* zdt = (float*)(ws + o_zdt);
  unsigned short* zxb  = (unsigned short*)(ws + o_zxb);
  unsigned short* xbcf = (unsigned short*)(ws + o_xbcf);
  unsigned short* xbcb = (unsigned short*)(ws + o_xbcb);
  unsigned short* yf  = (unsigned short*)(ws + o_yf);
  unsigned short* yb  = (unsigned short*)(ws + o_yb);
  unsigned short* comb = (unsigned short*)(ws + o_comb);
  unsigned short* mo  = (unsigned short*)(ws + o_mo);
  float* hln = (float*)(ws + o_hln);
  unsigned short* hbf = (unsigned short*)(ws + o_hbf);
  unsigned short* h1b = (unsigned short*)(ws + o_h1);
  unsigned short* f2  = (unsigned short*)(ws + o_f2);

  // ---- all bf16 conversions in one launch ----
  {
    int n = NTOK * DMODEL + DPROJP * DMODEL + DMODEL * DINNER + DFFN * DMODEL + DMODEL * DFFN;
    cvt_all<<<(n + 255) / 256, 256, 0, stream>>>(item_emb, in_proj_w, out_proj_w, w1, w2,
                                                 u_bf, winb, woutb, w1b, w2b);
  }

  // ---- in-proj: zxb[8192,2192](bf16) = u @ in_proj_w^T ; dt cols fp32 -> zdt ----
  gemm_bt<2><<<dim3(DPROJP / 128, NTOK / 128), 256, 0, stream>>>(
      u_bf, winb, zxb, nullptr, zdt, DMODEL, DMODEL, DPROJ, 0);

  // ---- dt (softplus) + conv for B/C channels (merged; x-conv fused into ssd) ----
  dt_conv_bc<<<1152, 256, 0, stream>>>(zdt, dt_bias, dtf, dtb,
                                       zxb, conv_w, conv_b, xbcf, xbcb);

  // ---- chunked SSD with fused x-conv: 256 blocks = (dir,b,h), 8 waves each ----
  ssd_chunk<<<256, 512, 0, stream>>>(zxb, xbcf, xbcb, conv_w, conv_b,
                                     dtf, dtb, A_log, Dp, yf, yb);

  // ---- fused gate + RMS + dir-combine -> comb[8192,1024] bf16 ----
  gate_rms_comb<<<NTOK, 256, 0, stream>>>(yf, yb, zxb, norm_w, comb);

  // ---- out-proj: mo = comb @ out_proj_w^T, split-K=2 (bf16 partials) ----
  gemm_bt<3><<<dim3(DMODEL / 128, NTOK / 128, 2), 256, 0, stream>>>(
      comb, woutb, mo, nullptr, nullptr, DINNER / 2, DINNER, DMODEL,
      (size_t)NTOK * DMODEL);

  // ---- combine + first layernorm (sums 2 partials) ----
  combine_ln<<<NTOK, 256, 0, stream>>>(mo, item_emb, ln_w, ln_b, hln, hbf);

  // ---- FFN1: h1 = gelu(hln @ w1^T + b1) -> bf16 ----
  gemm_bt<1><<<dim3(DFFN / 128, NTOK / 128), 256, 0, stream>>>(
      hbf, w1b, h1b, b1, nullptr, DMODEL, DMODEL, DFFN, 0);

  // ---- FFN2: f2 = h1 @ w2^T, split-K=2 (bf16 partials; bias b2 in final_ln) ----
  gemm_bt<3><<<dim3(DMODEL / 128, NTOK / 128, 2), 256, 0, stream>>>(
      h1b, w2b, f2, nullptr, nullptr, DFFN / 2, DFFN, DMODEL,
      (size_t)NTOK * DMODEL);

  // ---- final layernorm (sums 2 partials + b2) -> d_out ----
  final_ln<<<NTOK, 256, 0, stream>>>(f2, b2, hln, fln_w, fln_b, outp);

  (void)in_sizes; (void)n_in; (void)out_size; (void)ws_size;
}